// Round 18
// baseline (268.577 us; speedup 1.0000x reference)
//
#include <hip/hip_runtime.h>
#include <math.h>

// ---- problem constants (fixed shapes) ----
#define NPTS 16384
#define DIM  512
#define KSEL 11                   // K+1 smallest incl. self; min dropped at the end
#define NSPLIT 16
#define CPS   (NPTS / NSPLIT)     // 1024 columns per split (main)
#define BMM   128                 // knn_main rows per block (4 waves x 32 rows)
#define BMT   128                 // thresh rows per block (4 waves x 32 rows)
#define BNM   32                  // main: columns per tile (16 KB) -> 4 blocks/CU
#define BNT   32                  // thresh: columns per tile (16 KB) -> 4 blocks/CU
#define MITERS (CPS / BNM)        // 32 main iterations per split
#define NCH   8                   // thresh chunks
#define TITERS 16                 // threshold pass: 512 cols per chunk-sample
#define TCH   2048                // thresh chunk stride (sample = first 512 of each)
#define STRIPB 8192               // bytes per 16-row/col fragment-major strip (i8)
#define CAP   16                  // appended candidates per (row, split)
#define QS    22.0f               // quantization scale: x_i8 = clamp(rint(22 x), +-127)

typedef __attribute__((ext_vector_type(4))) int i32x4;

__device__ __forceinline__ void gload_lds16(const void* g, void* l) {
    __builtin_amdgcn_global_load_lds(
        (const __attribute__((address_space(1))) void*)g,
        (__attribute__((address_space(3))) void*)l, 16, 0, 0);
}

__device__ __forceinline__ void pinreg(i32x4& v) { asm volatile("" : "+v"(v)); }
__device__ __forceinline__ void pini(int& v)     { asm volatile("" : "+v"(v)); }

// exact KSEL-smallest scan over ints v[0..n), n >= KSEL; a[] gets them; returns the KSEL-th
__device__ __forceinline__ int topk_scan_i(const int* v, int n, int* a) {
    #pragma unroll
    for (int p = 0; p < KSEL; ++p) a[p] = v[p];
    int mx = a[0];
    #pragma unroll
    for (int p = 1; p < KSEL; ++p) mx = max(mx, a[p]);
    for (int i = KSEL; i < n; ++i) {
        const int x = v[i];
        if (x < mx) {
            bool done = false;
            #pragma unroll
            for (int p = 0; p < KSEL; ++p) {
                const bool rep = (!done) && (a[p] == mx);
                a[p] = rep ? x : a[p];
                done = done || rep;
            }
            mx = a[0];
            #pragma unroll
            for (int p = 1; p < KSEL; ++p) mx = max(mx, a[p]);
        }
    }
    return mx;
}

// ---- kernel 1: fp32 -> i8 quantize into K=64 fragment-major layout + sqi = ||xi8||^2
//   byte(row,k) = (row>>4)*8192 + (k>>6)*1024 + ((k>>4)&3)*256 + (row&15)*16 + (k&15)
__global__ void prep_convert(const float* __restrict__ obs, char* __restrict__ obsb,
                             int* __restrict__ sqi) {
    const int wv = threadIdx.x >> 6, ln = threadIdx.x & 63;
    const int row = blockIdx.x * 4 + wv;
    const float4* s = (const float4*)(obs + (unsigned long)row * DIM + ln * 8);
    const float4 a = s[0], b = s[1];
    float xs[8] = {a.x, a.y, a.z, a.w, b.x, b.y, b.z, b.w};
    unsigned long u = 0ul;
    int ssum = 0;
    #pragma unroll
    for (int j = 0; j < 8; ++j) {
        const int q = __float2int_rn(fminf(fmaxf(xs[j] * QS, -127.f), 127.f));
        ssum += q * q;
        u |= ((unsigned long)((unsigned)q & 0xffu)) << (8 * j);
    }
    *(unsigned long*)(obsb + (unsigned long)(row >> 4) * STRIPB + (ln >> 3) * 1024
                      + ((ln >> 1) & 3) * 256 + (row & 15) * 16 + (ln & 1) * 8) = u;
    #pragma unroll
    for (int off = 32; off; off >>= 1) ssum += __shfl_xor(ssum, off);
    if (ln == 0) sqi[row] = ssum;
}

// ---- staging macro: 32-col tile = 2 strips = 16 KB; wave wv stages quarter wv
#define STAGE_M(BUF, CITER) do {                                                \
        const char* gs_ = obsb + (unsigned long)((C0 >> 4) + 2 * (CITER)) * STRIPB \
                          + wv * 4096 + ln * 16;                                \
        char* lb_ = &Braw[BUF][0] + wv * 4096;                                  \
        _Pragma("unroll")                                                       \
        for (int r_ = 0; r_ < 4; ++r_)                                          \
            gload_lds16(gs_ + r_ * 1024, lb_ + r_ * 1024);                      \
    } while (0)

// ---- kernel 2: threshold pass — 4 blocks/CU geometry (R17 occupancy fix applied).
//   Per (row-tile, chunk q of 8): 11 smallest of 32 slot-minima over 512 distinct
//   cols (each an ACTUAL int distance) -> Tv[row][q][11].
__global__ __launch_bounds__(256, 4) void thresh_pass(
    const char* __restrict__ obsb, const int* __restrict__ sqi,
    int* __restrict__ Tv)
{
    __shared__ __align__(16) char Braw[2][BNT * 512];   // 32 KB double buffer

    const int tid = threadIdx.x;
    const int wv = tid >> 6, ln = tid & 63;
    const int q  = blockIdx.x >> 7;          // chunk 0..7
    const int rt = blockIdx.x & 127;         // row tile 0..127
    const int R0 = rt * BMT;
    const int C0 = q * TCH;                  // sample = first 512 cols of chunk q
    const int wrow0 = R0 + wv * 32;
    const int lr = ln & 15;
    const int kc = ln >> 4;
    const int lfrag = kc * 256 + lr * 16;

    i32x4 afrag[2][8];
    int sqr[2];
    #pragma unroll
    for (int s = 0; s < 2; ++s) {
        const unsigned long sbase = (unsigned long)((R0 >> 4) + wv * 2 + s) * STRIPB;
        #pragma unroll
        for (int t = 0; t < 8; ++t) {
            afrag[s][t] = *(const i32x4*)(obsb + sbase + t * 1024 + lfrag);
            pinreg(afrag[s][t]);
        }
        sqr[s] = sqi[wrow0 + s * 16 + lr];
        pini(sqr[s]);
    }

    int segmin[2][8];
    #pragma unroll
    for (int s = 0; s < 2; ++s)
        #pragma unroll
        for (int p = 0; p < 8; ++p) segmin[s][p] = 0x7FFFFFFF;

    STAGE_M(0, 0);
    __syncthreads();
    #pragma unroll 2
    for (int it = 0; it < TITERS; ++it) {
        const int cur = it & 1;
        if (it + 1 < TITERS) STAGE_M(cur ^ 1, it + 1);
        const char* bp = &Braw[cur][0];
        i32x4 acc[2][2];
        #pragma unroll
        for (int s_ = 0; s_ < 2; ++s_)
            #pragma unroll
            for (int c_ = 0; c_ < 2; ++c_) acc[s_][c_] = (i32x4){0, 0, 0, 0};
        #pragma unroll
        for (int cg = 0; cg < 2; ++cg)
            #pragma unroll
            for (int t = 0; t < 8; ++t) {
                const i32x4 b = *(const i32x4*)(bp + cg * STRIPB + t * 1024 + lfrag);
                acc[0][cg] = __builtin_amdgcn_mfma_i32_16x16x64_i8(b, afrag[0][t], acc[0][cg], 0, 0, 0);
                acc[1][cg] = __builtin_amdgcn_mfma_i32_16x16x64_i8(b, afrag[1][t], acc[1][cg], 0, 0, 0);
            }
        i32x4 sqv[2];
        #pragma unroll
        for (int c_ = 0; c_ < 2; ++c_)
            sqv[c_] = *(const i32x4*)(sqi + C0 + it * BNT + c_ * 16 + kc * 4);
        #pragma unroll
        for (int s = 0; s < 2; ++s)
            #pragma unroll
            for (int cg = 0; cg < 2; ++cg)
                #pragma unroll
                for (int r = 0; r < 4; ++r) {
                    const int v = sqr[s] + sqv[cg][r] - 2 * acc[s][cg][r];
                    segmin[s][cg * 4 + r] = min(segmin[s][cg * 4 + r], v);
                }
        __syncthreads();
    }

    // gather 32 slot-minima per row (stride 33) -> 11 smallest -> Tv[row][q][11]
    int* mins = (int*)&Braw[0][0];               // [BMT][33] = 16.9 KB
    #pragma unroll
    for (int s = 0; s < 2; ++s)
        #pragma unroll
        for (int p = 0; p < 8; ++p)
            mins[(wv * 32 + s * 16 + lr) * 33 + kc * 8 + p] = segmin[s][p];
    __syncthreads();
    if (tid < BMT) {
        int a[KSEL];
        topk_scan_i(mins + tid * 33, 32, a);
        #pragma unroll
        for (int p = 0; p < KSEL; ++p)
            Tv[(unsigned long)(R0 + tid) * (NCH * KSEL) + q * KSEL + p] = a[p];
    }
}

// ---- kernel 3: T[row] = 11th smallest of the 88 chunk values
//   (88 actual distances at distinct columns => provable upper bound of true 11th)
__global__ void tmerge(const int* __restrict__ Tv, int* __restrict__ T) {
    const int row = blockIdx.x * 256 + threadIdx.x;
    int a[KSEL];
    T[row] = topk_scan_i(Tv + (unsigned long)row * (NCH * KSEL), NCH * KSEL, a);
}

// ---- kernel 4: main pass (R17-identical) — BMM=128, 2 strips/wave, BN=32, 4 blocks/CU
__global__ __launch_bounds__(256, 4) void knn_main(
    const char* __restrict__ obsb, const int* __restrict__ sqi,
    const int* __restrict__ T, int* __restrict__ cnt,
    int* __restrict__ vals)
{
    __shared__ __align__(16) char Braw[2][BNM * 512];   // 32 KB double buffer
    __shared__ unsigned lcnt[BMM];                      // 0.5 KB

    const int tid = threadIdx.x;
    const int wv = tid >> 6, ln = tid & 63;
    const int sp = blockIdx.x >> 7;          // split 0..15
    const int rt = blockIdx.x & 127;         // row tile 0..127
    const int R0 = rt * BMM;
    const int C0 = sp * CPS;
    const int wrow0 = R0 + wv * 32;
    const int lr = ln & 15;
    const int kc = ln >> 4;
    const int lfrag = kc * 256 + lr * 16;

    if (tid < BMM) lcnt[tid] = 0u;

    i32x4 afrag[2][8];
    int sqr[2];
    #pragma unroll
    for (int s = 0; s < 2; ++s) {
        const unsigned long sbase = (unsigned long)((R0 >> 4) + wv * 2 + s) * STRIPB;
        #pragma unroll
        for (int t = 0; t < 8; ++t) {
            afrag[s][t] = *(const i32x4*)(obsb + sbase + t * 1024 + lfrag);
            pinreg(afrag[s][t]);
        }
        sqr[s] = sqi[wrow0 + s * 16 + lr];
        pini(sqr[s]);
    }

    unsigned lrow[2]; int tval[2]; int* vbase[2];
    #pragma unroll
    for (int s = 0; s < 2; ++s) {
        const int row = wrow0 + s * 16 + lr;
        lrow[s]  = wv * 32 + s * 16 + lr;
        tval[s]  = T[row];                   // exact int gate
        pini(tval[s]);
        vbase[s] = vals + ((unsigned long)row * NSPLIT + sp) * CAP;
    }

    STAGE_M(0, 0);
    __syncthreads();
    #pragma unroll 2
    for (int it = 0; it < MITERS; ++it) {
        const int cur = it & 1;
        if (it + 1 < MITERS) STAGE_M(cur ^ 1, it + 1);
        const char* bp = &Braw[cur][0];
        i32x4 acc[2][2];
        #pragma unroll
        for (int s_ = 0; s_ < 2; ++s_)
            #pragma unroll
            for (int c_ = 0; c_ < 2; ++c_) acc[s_][c_] = (i32x4){0, 0, 0, 0};
        #pragma unroll
        for (int cg = 0; cg < 2; ++cg)
            #pragma unroll
            for (int t = 0; t < 8; ++t) {
                const i32x4 b = *(const i32x4*)(bp + cg * STRIPB + t * 1024 + lfrag);
                acc[0][cg] = __builtin_amdgcn_mfma_i32_16x16x64_i8(b, afrag[0][t], acc[0][cg], 0, 0, 0);
                acc[1][cg] = __builtin_amdgcn_mfma_i32_16x16x64_i8(b, afrag[1][t], acc[1][cg], 0, 0, 0);
            }
        i32x4 sqv[2];
        #pragma unroll
        for (int c_ = 0; c_ < 2; ++c_)
            sqv[c_] = *(const i32x4*)(sqi + C0 + it * BNM + c_ * 16 + kc * 4);
        #pragma unroll
        for (int s_ = 0; s_ < 2; ++s_)
            #pragma unroll
            for (int cg = 0; cg < 2; ++cg)
                #pragma unroll
                for (int r = 0; r < 4; ++r) {
                    const int v_ = sqr[s_] + sqv[cg][r] - 2 * acc[s_][cg][r];
                    if (v_ <= tval[s_]) {
                        const unsigned i_ = atomicAdd(&lcnt[lrow[s_]], 1u);
                        if (i_ < CAP) vbase[s_][i_] = v_;
                    }
                }
        __syncthreads();
    }

    if (tid < BMM) {
        const unsigned c = lcnt[tid];
        cnt[(unsigned long)(R0 + tid) * NSPLIT + sp] = (int)(c < CAP ? c : CAP);
    }
}

// ---- kernel 5: per row, exact top-11 of appended int candidates -> output
__global__ void merge_out(const int* __restrict__ cnt, const int* __restrict__ vals,
                          float* __restrict__ out) {
    const int row = blockIdx.x * 256 + threadIdx.x;
    int arr[KSEL];
    #pragma unroll
    for (int p = 0; p < KSEL; ++p) arr[p] = 0x7FFFFFFF;
    int mx = 0x7FFFFFFF;
    for (int q = 0; q < NSPLIT; ++q) {
        const int n = min(cnt[(unsigned long)row * NSPLIT + q], CAP);
        const int* base = vals + ((unsigned long)row * NSPLIT + q) * CAP;
        for (int i = 0; i < n; ++i) {
            const int x = base[i];
            if (x < mx) {
                bool done = false;
                #pragma unroll
                for (int p = 0; p < KSEL; ++p) {
                    const bool rep = (!done) && (arr[p] == mx);
                    arr[p] = rep ? x : arr[p];
                    done = done || rep;
                }
                mx = arr[0];
                #pragma unroll
                for (int p = 1; p < KSEL; ++p) mx = max(mx, arr[p]);
            }
        }
    }
    int mn = arr[0];
    #pragma unroll
    for (int p = 1; p < KSEL; ++p) mn = min(mn, arr[p]);
    float ssum = 0.f;
    #pragma unroll
    for (int p = 0; p < KSEL; ++p) ssum += sqrtf((float)max(arr[p], 0));
    const float smn = sqrtf((float)max(mn, 0));
    out[row] = log1pf((ssum - smn) * (0.1f / QS));   // r = sqrt(d2i)/QS; mean of 10
}

extern "C" void kernel_launch(void* const* d_in, const int* in_sizes, int n_in,
                              void* d_out, int out_size, void* d_ws, size_t ws_size,
                              hipStream_t stream) {
    const float* obs = (const float*)d_in[0];
    float* out = (float*)d_out;
    char* ws = (char*)d_ws;

    char* obsb = ws;                                         // 8 MB fragment-major i8
    int*  sqi  = (int*)(ws + (size_t)NPTS * 512);            // 64 KB
    int*  T    = sqi + NPTS;                                 // 64 KB
    int*  cnt  = T + NPTS;                                   // 1 MB
    int*  vals = cnt + NPTS * NSPLIT;                        // 16.8 MB (16 x CAP=16)
    int*  Tv   = vals;   // aliased: Tv (5.8 MB) consumed by tmerge BEFORE
                         // knn_main writes vals (stream-ordered, no overlap)

    prep_convert<<<NPTS / 4, 256, 0, stream>>>(obs, obsb, sqi);
    thresh_pass<<<128 * NCH, 256, 0, stream>>>(obsb, sqi, Tv);
    tmerge<<<NPTS / 256, 256, 0, stream>>>(Tv, T);
    knn_main<<<128 * NSPLIT, 256, 0, stream>>>(obsb, sqi, T, cnt, vals);
    merge_out<<<NPTS / 256, 256, 0, stream>>>(cnt, vals, out);
}

// Round 19
// 253.350 us; speedup vs baseline: 1.0601x; 1.0601x over previous
//
#include <hip/hip_runtime.h>
#include <math.h>

// ---- problem constants (fixed shapes) ----
#define NPTS 16384
#define DIM  512
#define KSEL 11                   // K+1 smallest incl. self; min dropped at the end
#define NSPLIT 16
#define CPS   (NPTS / NSPLIT)     // 1024 columns per split (main)
#define BMM   128                 // knn_main rows per block (4 waves x 32 rows)
#define BMT   128                 // thresh rows per block (4 waves x 32 rows)
#define BNM   32                  // main: columns per tile (16 KB) -> 4 blocks/CU
#define BNT   64                  // thresh: columns per tile (32 KB, R14-proven)
#define MITERS (CPS / BNM)        // 32 main iterations per split
#define TITERS 16                 // threshold pass: 1024 cols per quarter-sample
#define TCH   4096                // thresh quarter stride
#define STRIPB 8192               // bytes per 16-row/col fragment-major strip (i8)
#define CAP   16                  // appended candidates per (row, split)
#define QS    22.0f               // quantization scale: x_i8 = clamp(rint(22 x), +-127)

typedef __attribute__((ext_vector_type(4))) int i32x4;

__device__ __forceinline__ void gload_lds16(const void* g, void* l) {
    __builtin_amdgcn_global_load_lds(
        (const __attribute__((address_space(1))) void*)g,
        (__attribute__((address_space(3))) void*)l, 16, 0, 0);
}

__device__ __forceinline__ void pinreg(i32x4& v) { asm volatile("" : "+v"(v)); }
__device__ __forceinline__ void pini(int& v)     { asm volatile("" : "+v"(v)); }

// exact KSEL-smallest scan over ints v[0..n), n >= KSEL; a[] gets them; returns the KSEL-th
__device__ __forceinline__ int topk_scan_i(const int* v, int n, int* a) {
    #pragma unroll
    for (int p = 0; p < KSEL; ++p) a[p] = v[p];
    int mx = a[0];
    #pragma unroll
    for (int p = 1; p < KSEL; ++p) mx = max(mx, a[p]);
    for (int i = KSEL; i < n; ++i) {
        const int x = v[i];
        if (x < mx) {
            bool done = false;
            #pragma unroll
            for (int p = 0; p < KSEL; ++p) {
                const bool rep = (!done) && (a[p] == mx);
                a[p] = rep ? x : a[p];
                done = done || rep;
            }
            mx = a[0];
            #pragma unroll
            for (int p = 1; p < KSEL; ++p) mx = max(mx, a[p]);
        }
    }
    return mx;
}

// ---- kernel 1: fp32 -> i8 quantize into K=64 fragment-major layout + sqi = ||xi8||^2
//   byte(row,k) = (row>>4)*8192 + (k>>6)*1024 + ((k>>4)&3)*256 + (row&15)*16 + (k&15)
__global__ void prep_convert(const float* __restrict__ obs, char* __restrict__ obsb,
                             int* __restrict__ sqi) {
    const int wv = threadIdx.x >> 6, ln = threadIdx.x & 63;
    const int row = blockIdx.x * 4 + wv;
    const float4* s = (const float4*)(obs + (unsigned long)row * DIM + ln * 8);
    const float4 a = s[0], b = s[1];
    float xs[8] = {a.x, a.y, a.z, a.w, b.x, b.y, b.z, b.w};
    unsigned long u = 0ul;
    int ssum = 0;
    #pragma unroll
    for (int j = 0; j < 8; ++j) {
        const int q = __float2int_rn(fminf(fmaxf(xs[j] * QS, -127.f), 127.f));
        ssum += q * q;
        u |= ((unsigned long)((unsigned)q & 0xffu)) << (8 * j);
    }
    *(unsigned long*)(obsb + (unsigned long)(row >> 4) * STRIPB + (ln >> 3) * 1024
                      + ((ln >> 1) & 3) * 256 + (row & 15) * 16 + (ln & 1) * 8) = u;
    #pragma unroll
    for (int off = 32; off; off >>= 1) ssum += __shfl_xor(ssum, off);
    if (ln == 0) sqi[row] = ssum;
}

// ---- staging macros (lane-linear, layout-baked) ----
// thresh tile: 64 cols = 4 strips = 32 KB; wave wv stages strip wv
#define STAGE_T(BUF, CITER) do {                                                \
        const char* gs_ = obsb + (unsigned long)((C0 >> 4) + 4 * (CITER)) * STRIPB \
                          + wv * 8192 + ln * 16;                                \
        char* lb_ = &Braw[BUF][0] + wv * 8192;                                  \
        _Pragma("unroll")                                                       \
        for (int r_ = 0; r_ < 8; ++r_)                                          \
            gload_lds16(gs_ + r_ * 1024, lb_ + r_ * 1024);                      \
    } while (0)

// main tile: 32 cols = 2 strips = 16 KB; wave wv stages quarter wv
#define STAGE_M(BUF, CITER) do {                                                \
        const char* gs_ = obsb + (unsigned long)((C0 >> 4) + 2 * (CITER)) * STRIPB \
                          + wv * 4096 + ln * 16;                                \
        char* lb_ = &Braw[BUF][0] + wv * 4096;                                  \
        _Pragma("unroll")                                                       \
        for (int r_ = 0; r_ < 4; ++r_)                                          \
            gload_lds16(gs_ + r_ * 1024, lb_ + r_ * 1024);                      \
    } while (0)

// ---- kernel 2: threshold pass (R14/R17-proven geometry) — per (row-tile, quarter):
//   11 smallest of 64 slot-minima over 1024 distinct cols (ACTUAL int distances) -> Tv
__global__ __launch_bounds__(256, 2) void thresh_pass(
    const char* __restrict__ obsb, const int* __restrict__ sqi,
    int* __restrict__ Tv)
{
    __shared__ __align__(16) char Braw[2][BNT * 512];   // 64 KB double buffer

    const int tid = threadIdx.x;
    const int wv = tid >> 6, ln = tid & 63;
    const int q  = blockIdx.x >> 7;          // quarter-sample 0..3
    const int rt = blockIdx.x & 127;         // row tile 0..127
    const int R0 = rt * BMT;
    const int C0 = q * TCH;                  // sample = first 1024 cols of chunk q
    const int wrow0 = R0 + wv * 32;
    const int lr = ln & 15;
    const int kc = ln >> 4;
    const int lfrag = kc * 256 + lr * 16;

    i32x4 afrag[2][8];
    int sqr[2];
    #pragma unroll
    for (int s = 0; s < 2; ++s) {
        const unsigned long sbase = (unsigned long)((R0 >> 4) + wv * 2 + s) * STRIPB;
        #pragma unroll
        for (int t = 0; t < 8; ++t) {
            afrag[s][t] = *(const i32x4*)(obsb + sbase + t * 1024 + lfrag);
            pinreg(afrag[s][t]);
        }
        sqr[s] = sqi[wrow0 + s * 16 + lr];
        pini(sqr[s]);
    }

    int segmin[2][16];
    #pragma unroll
    for (int s = 0; s < 2; ++s)
        #pragma unroll
        for (int p = 0; p < 16; ++p) segmin[s][p] = 0x7FFFFFFF;

    STAGE_T(0, 0);
    __syncthreads();
    #pragma unroll 2
    for (int it = 0; it < TITERS; ++it) {
        const int cur = it & 1;
        if (it + 1 < TITERS) STAGE_T(cur ^ 1, it + 1);
        const char* bp = &Braw[cur][0];
        i32x4 acc[2][4];
        #pragma unroll
        for (int s_ = 0; s_ < 2; ++s_)
            #pragma unroll
            for (int c_ = 0; c_ < 4; ++c_) acc[s_][c_] = (i32x4){0, 0, 0, 0};
        #pragma unroll
        for (int cg = 0; cg < 4; ++cg)
            #pragma unroll
            for (int t = 0; t < 8; ++t) {
                const i32x4 b = *(const i32x4*)(bp + cg * STRIPB + t * 1024 + lfrag);
                acc[0][cg] = __builtin_amdgcn_mfma_i32_16x16x64_i8(b, afrag[0][t], acc[0][cg], 0, 0, 0);
                acc[1][cg] = __builtin_amdgcn_mfma_i32_16x16x64_i8(b, afrag[1][t], acc[1][cg], 0, 0, 0);
            }
        i32x4 sqv[4];
        #pragma unroll
        for (int c_ = 0; c_ < 4; ++c_)
            sqv[c_] = *(const i32x4*)(sqi + C0 + it * BNT + c_ * 16 + kc * 4);
        #pragma unroll
        for (int s = 0; s < 2; ++s)
            #pragma unroll
            for (int cg = 0; cg < 4; ++cg)
                #pragma unroll
                for (int r = 0; r < 4; ++r) {
                    const int v = sqr[s] + sqv[cg][r] - 2 * acc[s][cg][r];
                    segmin[s][cg * 4 + r] = min(segmin[s][cg * 4 + r], v);
                }
        __syncthreads();
    }

    int* mins = (int*)&Braw[0][0];               // [BMT][65] = 33 KB
    #pragma unroll
    for (int s = 0; s < 2; ++s)
        #pragma unroll
        for (int p = 0; p < 16; ++p)
            mins[(wv * 32 + s * 16 + lr) * 65 + kc * 16 + p] = segmin[s][p];
    __syncthreads();
    if (tid < BMT) {
        int a[KSEL];
        topk_scan_i(mins + tid * 65, 64, a);
        #pragma unroll
        for (int p = 0; p < KSEL; ++p)
            Tv[(unsigned long)(R0 + tid) * (4 * KSEL) + q * KSEL + p] = a[p];
    }
}

// ---- kernel 3: T[row] = 11th smallest of the 44 quarter values (provable upper bound)
__global__ void tmerge(const int* __restrict__ Tv, int* __restrict__ T) {
    const int row = blockIdx.x * 256 + threadIdx.x;
    int a[KSEL];
    T[row] = topk_scan_i(Tv + (unsigned long)row * (4 * KSEL), 4 * KSEL, a);
}

// ---- kernel 4: main pass — BMM=128, 2 strips/wave (64 VGPR afrag), BN=32,
//   4 blocks/CU (4 waves/SIMD): the R17 occupancy configuration.
__global__ __launch_bounds__(256, 4) void knn_main(
    const char* __restrict__ obsb, const int* __restrict__ sqi,
    const int* __restrict__ T, int* __restrict__ cnt,
    int* __restrict__ vals)
{
    __shared__ __align__(16) char Braw[2][BNM * 512];   // 32 KB double buffer
    __shared__ unsigned lcnt[BMM];                      // 0.5 KB

    const int tid = threadIdx.x;
    const int wv = tid >> 6, ln = tid & 63;
    const int sp = blockIdx.x >> 7;          // split 0..15
    const int rt = blockIdx.x & 127;         // row tile 0..127
    const int R0 = rt * BMM;
    const int C0 = sp * CPS;
    const int wrow0 = R0 + wv * 32;
    const int lr = ln & 15;
    const int kc = ln >> 4;
    const int lfrag = kc * 256 + lr * 16;

    if (tid < BMM) lcnt[tid] = 0u;

    // A fragments: 2 strips x 8 t-steps (64 VGPRs), pinned — fits the 128-VGPR cap
    i32x4 afrag[2][8];
    int sqr[2];
    #pragma unroll
    for (int s = 0; s < 2; ++s) {
        const unsigned long sbase = (unsigned long)((R0 >> 4) + wv * 2 + s) * STRIPB;
        #pragma unroll
        for (int t = 0; t < 8; ++t) {
            afrag[s][t] = *(const i32x4*)(obsb + sbase + t * 1024 + lfrag);
            pinreg(afrag[s][t]);
        }
        sqr[s] = sqi[wrow0 + s * 16 + lr];
        pini(sqr[s]);
    }

    unsigned lrow[2]; int tval[2]; int* vbase[2];
    #pragma unroll
    for (int s = 0; s < 2; ++s) {
        const int row = wrow0 + s * 16 + lr;
        lrow[s]  = wv * 32 + s * 16 + lr;
        tval[s]  = T[row];                   // exact int gate
        pini(tval[s]);
        vbase[s] = vals + ((unsigned long)row * NSPLIT + sp) * CAP;
    }

    STAGE_M(0, 0);
    __syncthreads();
    #pragma unroll 2
    for (int it = 0; it < MITERS; ++it) {
        const int cur = it & 1;
        if (it + 1 < MITERS) STAGE_M(cur ^ 1, it + 1);
        // GEMM: 16 ds_read_b128, 32 MFMA 16x16x64 (each b reused 2x)
        const char* bp = &Braw[cur][0];
        i32x4 acc[2][2];
        #pragma unroll
        for (int s_ = 0; s_ < 2; ++s_)
            #pragma unroll
            for (int c_ = 0; c_ < 2; ++c_) acc[s_][c_] = (i32x4){0, 0, 0, 0};
        #pragma unroll
        for (int cg = 0; cg < 2; ++cg)
            #pragma unroll
            for (int t = 0; t < 8; ++t) {
                const i32x4 b = *(const i32x4*)(bp + cg * STRIPB + t * 1024 + lfrag);
                acc[0][cg] = __builtin_amdgcn_mfma_i32_16x16x64_i8(b, afrag[0][t], acc[0][cg], 0, 0, 0);
                acc[1][cg] = __builtin_amdgcn_mfma_i32_16x16x64_i8(b, afrag[1][t], acc[1][cg], 0, 0, 0);
            }
        i32x4 sqv[2];
        #pragma unroll
        for (int c_ = 0; c_ < 2; ++c_)
            sqv[c_] = *(const i32x4*)(sqi + C0 + it * BNM + c_ * 16 + kc * 4);
        // rare predicated append (exact int gate)
        #pragma unroll
        for (int s_ = 0; s_ < 2; ++s_)
            #pragma unroll
            for (int cg = 0; cg < 2; ++cg)
                #pragma unroll
                for (int r = 0; r < 4; ++r) {
                    const int v_ = sqr[s_] + sqv[cg][r] - 2 * acc[s_][cg][r];
                    if (v_ <= tval[s_]) {
                        const unsigned i_ = atomicAdd(&lcnt[lrow[s_]], 1u);
                        if (i_ < CAP) vbase[s_][i_] = v_;
                    }
                }
        __syncthreads();
    }

    if (tid < BMM) {
        const unsigned c = lcnt[tid];
        cnt[(unsigned long)(R0 + tid) * NSPLIT + sp] = (int)(c < CAP ? c : CAP);
    }
}

// ---- kernel 5: per row, exact top-11 of appended int candidates -> output
__global__ void merge_out(const int* __restrict__ cnt, const int* __restrict__ vals,
                          float* __restrict__ out) {
    const int row = blockIdx.x * 256 + threadIdx.x;
    int arr[KSEL];
    #pragma unroll
    for (int p = 0; p < KSEL; ++p) arr[p] = 0x7FFFFFFF;
    int mx = 0x7FFFFFFF;
    for (int q = 0; q < NSPLIT; ++q) {
        const int n = min(cnt[(unsigned long)row * NSPLIT + q], CAP);
        const int* base = vals + ((unsigned long)row * NSPLIT + q) * CAP;
        for (int i = 0; i < n; ++i) {
            const int x = base[i];
            if (x < mx) {
                bool done = false;
                #pragma unroll
                for (int p = 0; p < KSEL; ++p) {
                    const bool rep = (!done) && (arr[p] == mx);
                    arr[p] = rep ? x : arr[p];
                    done = done || rep;
                }
                mx = arr[0];
                #pragma unroll
                for (int p = 1; p < KSEL; ++p) mx = max(mx, arr[p]);
            }
        }
    }
    int mn = arr[0];
    #pragma unroll
    for (int p = 1; p < KSEL; ++p) mn = min(mn, arr[p]);
    float ssum = 0.f;
    #pragma unroll
    for (int p = 0; p < KSEL; ++p) ssum += sqrtf((float)max(arr[p], 0));
    const float smn = sqrtf((float)max(mn, 0));
    out[row] = log1pf((ssum - smn) * (0.1f / QS));   // r = sqrt(d2i)/QS; mean of 10
}

extern "C" void kernel_launch(void* const* d_in, const int* in_sizes, int n_in,
                              void* d_out, int out_size, void* d_ws, size_t ws_size,
                              hipStream_t stream) {
    const float* obs = (const float*)d_in[0];
    float* out = (float*)d_out;
    char* ws = (char*)d_ws;

    char* obsb = ws;                                         // 8 MB fragment-major i8
    int*  sqi  = (int*)(ws + (size_t)NPTS * 512);            // 64 KB
    int*  T    = sqi + NPTS;                                 // 64 KB
    int*  cnt  = T + NPTS;                                   // 1 MB
    int*  vals = cnt + NPTS * NSPLIT;                        // 16.8 MB (16 x CAP=16)
    int*  Tv   = vals;   // aliased: Tv (2.75 MB) consumed by tmerge BEFORE
                         // knn_main writes vals (stream-ordered, no overlap)

    prep_convert<<<NPTS / 4, 256, 0, stream>>>(obs, obsb, sqi);
    thresh_pass<<<128 * 4, 256, 0, stream>>>(obsb, sqi, Tv);
    tmerge<<<NPTS / 256, 256, 0, stream>>>(Tv, T);
    knn_main<<<128 * NSPLIT, 256, 0, stream>>>(obsb, sqi, T, cnt, vals);
    merge_out<<<NPTS / 256, 256, 0, stream>>>(cnt, vals, out);
}